// Round 5
// baseline (553.979 us; speedup 1.0000x reference)
//
#include <hip/hip_runtime.h>

#define NN 50000
#define EE 800000
#define DD 64
#define NL 3
#define UIN 832
#define XW 320   // stored x row: [h | mean | mx | mn | sd]
#define DELTA_F 2.833213344056216f
#define SLOPE 0.01f
#define SCAN_BLKS 196  // 196*256 = 50176 >= NN

typedef __attribute__((ext_vector_type(8))) short short8;
typedef __attribute__((ext_vector_type(4))) float floatx4;

// ---- static device buffers (fully rewritten every call) ----
__device__ __align__(16) float          g_hf[2][NN * DD];       // fp32 master h
__device__ __align__(16) unsigned short g_hb[2][NN * DD];       // bf16 copy for gathers
__device__ __align__(16) unsigned short g_msg[EE * DD];         // messages, CSR row order
__device__ __align__(16) unsigned short g_x2[NN * XW];          // [h | agg] bf16
__device__ __align__(16) float          g_sc[NN * 2];           // per-node (s1, s2)
__device__ __align__(16) unsigned short g_BfragU[NL * 26 * 4 * 512]; // W_comb^T fragments
__device__ __align__(16) unsigned short g_BfragM[NL * 4 * 4 * 512];  // M_w^T fragments
__device__ float g_bcomb[NL * DD];
__device__ int   g_cnt[NN];
__device__ int   g_roff[NN + 1];
__device__ __align__(16) int2 g_cedge[EE];   // (src,dst) per CSR row — one 8B record
__device__ int   g_bsum[SCAN_BLKS], g_boff[SCAN_BLKS];

__device__ __forceinline__ float bf2f(unsigned short u) {
  return __uint_as_float(((unsigned)u) << 16);
}
__device__ __forceinline__ unsigned short f2bf(float f) {
  unsigned u = __float_as_uint(f);
  return (unsigned short)((u + 0x7FFFu + ((u >> 16) & 1u)) >> 16);
}
__device__ __forceinline__ float lrelu(float x) { return x >= 0.f ? x : SLOPE * x; }

// ---- prep: h = round(h*100)/100, plus bf16 copy ----
__global__ void __launch_bounds__(256) k_prep(const float* __restrict__ h) {
  int i = blockIdx.x * 256 + threadIdx.x;
  if (i >= NN * DD) return;
  float v = rintf(h[i] * 100.f) / 100.f;
  g_hf[0][i] = v;
  g_hb[0][i] = f2bf(v);
}

__global__ void __launch_bounds__(256) k_zero() {
  int i = blockIdx.x * 256 + threadIdx.x;
  if (i < NN) g_cnt[i] = 0;
}

__global__ void __launch_bounds__(256) k_hist(const int* __restrict__ dst) {
  int i = blockIdx.x * 256 + threadIdx.x;
  if (i < EE) atomicAdd(&g_cnt[dst[i]], 1);
}

// ---- hierarchical scan: (a) per-block reduce, (b) scan partials, (c) in-block scan ----
__global__ void __launch_bounds__(256) k_scan_a() {
  __shared__ int sh[256];
  int t = threadIdx.x;
  int idx = blockIdx.x * 256 + t;
  sh[t] = (idx < NN) ? g_cnt[idx] : 0;
  __syncthreads();
  for (int off = 128; off > 0; off >>= 1) {
    if (t < off) sh[t] += sh[t + off];
    __syncthreads();
  }
  if (t == 0) g_bsum[blockIdx.x] = sh[0];
}

__global__ void __launch_bounds__(256) k_scan_b() {
  __shared__ int sh[256];
  int t = threadIdx.x;
  sh[t] = (t < SCAN_BLKS) ? g_bsum[t] : 0;
  __syncthreads();
  for (int off = 1; off < 256; off <<= 1) {
    int v = (t >= off) ? sh[t - off] : 0;
    __syncthreads();
    sh[t] += v;
    __syncthreads();
  }
  if (t < SCAN_BLKS) g_boff[t] = (t == 0) ? 0 : sh[t - 1];
}

__global__ void __launch_bounds__(256) k_scan_c() {
  __shared__ int sh[256];
  int t = threadIdx.x;
  int idx = blockIdx.x * 256 + t;
  int v = (idx < NN) ? g_cnt[idx] : 0;
  sh[t] = v;
  __syncthreads();
  for (int off = 1; off < 256; off <<= 1) {
    int x = (t >= off) ? sh[t - off] : 0;
    __syncthreads();
    sh[t] += x;
    __syncthreads();
  }
  if (idx < NN) g_roff[idx] = g_boff[blockIdx.x] + sh[t] - v;  // exclusive prefix
  if (blockIdx.x == 0 && t == 0) g_roff[NN] = EE;              // total is known
}

__global__ void __launch_bounds__(256) k_scatter(const int* __restrict__ src,
                                                 const int* __restrict__ dst) {
  int i = blockIdx.x * 256 + threadIdx.x;
  if (i < EE) {
    int d = dst[i];
    int p = atomicAdd(&g_cnt[d], 1);
    g_cedge[g_roff[d] + p] = make_int2(src[i], d);  // single 8B random write
  }
}

// ---- W_comb = mix_w @ U_w, written directly into MFMA B-fragment layout ----
__global__ void __launch_bounds__(256) k_wcomb(const float* __restrict__ Uw,
                                               const float* __restrict__ mixw) {
  int idx = blockIdx.x * 256 + threadIdx.x;  // NL*DD*UIN = 159744
  if (idx >= NL * DD * UIN) return;
  int l = idx / (DD * UIN);
  int rem = idx - l * (DD * UIN);
  int d = rem / UIN;
  int k = rem - d * UIN;
  const float* xw = mixw + (l * DD + d) * DD;
  const float* uc = Uw + (size_t)l * DD * UIN + k;
  float s = 0.f;
  for (int j = 0; j < DD; ++j) s += xw[j] * uc[(size_t)j * UIN];
  int kt = k >> 5, kr = k & 31, g = kr >> 3, j8 = kr & 7, nb = d >> 4;
  int ln = (g << 4) | (d & 15);
  g_BfragU[(((l * 26 + kt) * 4 + nb) << 9) + ln * 8 + j8] = f2bf(s);
}

__global__ void __launch_bounds__(256) k_mfrag(const float* __restrict__ Mw) {
  int idx = blockIdx.x * 256 + threadIdx.x;  // NL*DD*128 = 24576
  if (idx >= NL * DD * 128) return;
  int l = idx >> 13;
  int rem = idx & 8191;
  int d = rem >> 7;
  int k = rem & 127;
  float w = Mw[idx];
  int kt = k >> 5, kr = k & 31, g = kr >> 3, j8 = kr & 7, nb = d >> 4;
  int ln = (g << 4) | (d & 15);
  g_BfragM[(((l * 4 + kt) * 4 + nb) << 9) + ln * 8 + j8] = f2bf(w);
}

__global__ void __launch_bounds__(192) k_bcomb(const float* __restrict__ mixw,
                                               const float* __restrict__ Ub,
                                               const float* __restrict__ mixb) {
  int idx = threadIdx.x;  // 192
  int l = idx >> 6, d = idx & 63;
  const float* xw = mixw + (l * DD + d) * DD;
  const float* ub = Ub + l * DD;
  float s = 0.f;
  for (int j = 0; j < DD; ++j) s += xw[j] * ub[j];
  g_bcomb[idx] = s + mixb[idx];
}

// ---- edge GEMM: msg[row] = leaky(M @ [h_src || h_dst] + Mb), rows in CSR order ----
__global__ void __launch_bounds__(256) k_edge(const float* __restrict__ Mb,
                                              int L, int par) {
  int lane = threadIdx.x & 63;
  int wid = blockIdx.x * 4 + (threadIdx.x >> 6);
  int nw = gridDim.x * 4;
  short8 bf[16];
  const unsigned short* bp = g_BfragM + ((size_t)L * 16) * 512;
#pragma unroll
  for (int i = 0; i < 16; ++i)
    bf[i] = *(const short8*)(bp + i * 512 + lane * 8);
  float mb[4];
#pragma unroll
  for (int nb = 0; nb < 4; ++nb) mb[nb] = Mb[L * DD + nb * 16 + (lane & 15)];
  const unsigned short* hb = g_hb[par];
  int chunk = (lane >> 4) << 3;

  for (int wt = wid; wt < EE / 16; wt += nw) {
    int2 e = g_cedge[wt * 16 + (lane & 15)];   // coalesced 8B CSR edge record
    int sn = e.x, dn = e.y;
    floatx4 acc[4];
#pragma unroll
    for (int nb = 0; nb < 4; ++nb)
#pragma unroll
      for (int r = 0; r < 4; ++r) acc[nb][r] = 0.f;
#pragma unroll
    for (int kk = 0; kk < 4; ++kk) {
      int node = (kk < 2) ? sn : dn;
      short8 a = *(const short8*)(hb + node * DD + (kk & 1) * 32 + chunk);
#pragma unroll
      for (int nb = 0; nb < 4; ++nb)
        acc[nb] = __builtin_amdgcn_mfma_f32_16x16x32_bf16(a, bf[kk * 4 + nb], acc[nb], 0, 0, 0);
    }
#pragma unroll
    for (int nb = 0; nb < 4; ++nb) {
#pragma unroll
      for (int r = 0; r < 4; ++r) {
        float v = lrelu(acc[nb][r] + mb[nb]);
        int row = wt * 16 + 4 * (lane >> 4) + r;
        g_msg[row * DD + nb * 16 + (lane & 15)] = f2bf(v);
      }
    }
  }
}

// ---- per-node aggregation -> x2 row [h | mean | mx | mn | sd] + (s1,s2) ----
__global__ void __launch_bounds__(256) k_agg(int par) {
  int lane = threadIdx.x & 63;
  int n = blockIdx.x * 4 + (threadIdx.x >> 6);
  int r0 = g_roff[n], r1 = g_roff[n + 1];
  float s = 0.f, q = 0.f, mx = -3.4e38f, mn = 3.4e38f;
  for (int r = r0; r < r1; ++r) {
    float v = bf2f(g_msg[r * DD + lane]);
    s += v;
    q += v * v;
    mx = fmaxf(mx, v);
    mn = fminf(mn, v);
  }
  float deg = (float)(r1 - r0);
  float degc = fmaxf(deg, 1.f);
  float mean = s / degc;
  float var = fmaxf(q / degc - mean * mean, 0.f);
  float sd = sqrtf(var + 1e-30f);
  if (r1 == r0) { mx = 0.f; mn = 0.f; sd = 0.f; }
  float logd = logf(fmaxf(deg, 1.f) + 1.f);
  unsigned short* xp = g_x2 + (size_t)n * XW;
  xp[lane] = g_hb[par][n * DD + lane];
  xp[64 + lane] = f2bf(mean);
  xp[128 + lane] = f2bf(mx);
  xp[192 + lane] = f2bf(mn);
  xp[256 + lane] = f2bf(sd);
  if (lane == 0) {
    g_sc[n * 2]     = logd / DELTA_F;
    g_sc[n * 2 + 1] = DELTA_F / logd;
  }
}

// ---- fused U+mix GEMM with per-node scalers applied post-GEMM ----
// out = U0*[h|agg] + s1*(U2*agg) + s2*(U3*agg) + b_comb; then leaky, +h, relu
// one 16-row tile per wave: 3125 tiles, 782 blocks
__global__ void __launch_bounds__(256) k_update(int L, int par, float* __restrict__ out) {
  int lane = threadIdx.x & 63;
  int wt = blockIdx.x * 4 + (threadIdx.x >> 6);
  if (wt >= 3125) return;
  int rbase = wt * 16;
  int chunk = (lane >> 4) << 3;
  floatx4 acc0[4], acc2[4], acc3[4];
#pragma unroll
  for (int nb = 0; nb < 4; ++nb)
#pragma unroll
    for (int r = 0; r < 4; ++r) { acc0[nb][r] = 0.f; acc2[nb][r] = 0.f; acc3[nb][r] = 0.f; }
  const unsigned short* bp = g_BfragU + (size_t)L * 26 * 4 * 512;
  int rowA = rbase + (lane & 15);
  const unsigned short* ap = g_x2 + (size_t)rowA * XW;

  // group 0: kt 0..9 over x2 cols [0,320) — identity+unit-scaled agg blocks
  for (int kk = 0; kk < 10; ++kk) {
    short8 a = *(const short8*)(ap + kk * 32 + chunk);
    short8 b[4];
#pragma unroll
    for (int nb = 0; nb < 4; ++nb)
      b[nb] = *(const short8*)(bp + ((kk * 4 + nb) << 9) + lane * 8);
#pragma unroll
    for (int nb = 0; nb < 4; ++nb)
      acc0[nb] = __builtin_amdgcn_mfma_f32_16x16x32_bf16(a, b[nb], acc0[nb], 0, 0, 0);
  }
  // groups 2,3: kt 10..17 and 18..25 over the SAME agg cols [64,320)
  for (int kk = 0; kk < 8; ++kk) {
    short8 a = *(const short8*)(ap + 64 + kk * 32 + chunk);
    short8 b2[4], b3[4];
#pragma unroll
    for (int nb = 0; nb < 4; ++nb) {
      b2[nb] = *(const short8*)(bp + (((10 + kk) * 4 + nb) << 9) + lane * 8);
      b3[nb] = *(const short8*)(bp + (((18 + kk) * 4 + nb) << 9) + lane * 8);
    }
#pragma unroll
    for (int nb = 0; nb < 4; ++nb) {
      acc2[nb] = __builtin_amdgcn_mfma_f32_16x16x32_bf16(a, b2[nb], acc2[nb], 0, 0, 0);
      acc3[nb] = __builtin_amdgcn_mfma_f32_16x16x32_bf16(a, b3[nb], acc3[nb], 0, 0, 0);
    }
  }

  float bc[4];
#pragma unroll
  for (int nb = 0; nb < 4; ++nb) bc[nb] = g_bcomb[L * DD + nb * 16 + (lane & 15)];
  float csum[4] = {0.f, 0.f, 0.f, 0.f};
#pragma unroll
  for (int r = 0; r < 4; ++r) {
    int row = rbase + 4 * (lane >> 4) + r;
    float s1 = g_sc[row * 2], s2 = g_sc[row * 2 + 1];
#pragma unroll
    for (int nb = 0; nb < 4; ++nb) {
      int col = nb * 16 + (lane & 15);
      float y = lrelu(acc0[nb][r] + s1 * acc2[nb][r] + s2 * acc3[nb][r] + bc[nb]);
      float hn = fmaxf(y + g_hf[par][row * DD + col], 0.f);
      g_hf[par ^ 1][row * DD + col] = hn;
      g_hb[par ^ 1][row * DD + col] = f2bf(hn);
      if (L == 2) csum[nb] += hn;
    }
  }
  if (L == 2) {
#pragma unroll
    for (int nb = 0; nb < 4; ++nb) {
      csum[nb] += __shfl_xor(csum[nb], 16);
      csum[nb] += __shfl_xor(csum[nb], 32);
    }
    if ((lane >> 4) == 0) {
#pragma unroll
      for (int nb = 0; nb < 4; ++nb) atomicAdd(out + nb * 16 + lane, csum[nb]);
    }
  }
}

extern "C" void kernel_launch(void* const* d_in, const int* in_sizes, int n_in,
                              void* d_out, int out_size, void* d_ws, size_t ws_size,
                              hipStream_t stream) {
  const float* h    = (const float*)d_in[0];
  const int*   src  = (const int*)d_in[1];
  const int*   dst  = (const int*)d_in[2];
  const float* Mw   = (const float*)d_in[3];
  const float* Mb   = (const float*)d_in[4];
  const float* Uw   = (const float*)d_in[5];
  const float* Ub   = (const float*)d_in[6];
  const float* mixw = (const float*)d_in[7];
  const float* mixb = (const float*)d_in[8];
  float* out = (float*)d_out;

  hipMemsetAsync(out, 0, (size_t)out_size * sizeof(float), stream);

  k_prep<<<12500, 256, 0, stream>>>(h);
  // CSR build (dst constant across layers -> once per call)
  k_zero<<<196, 256, 0, stream>>>();
  k_hist<<<3125, 256, 0, stream>>>(dst);
  k_scan_a<<<SCAN_BLKS, 256, 0, stream>>>();
  k_scan_b<<<1, 256, 0, stream>>>();
  k_scan_c<<<SCAN_BLKS, 256, 0, stream>>>();
  k_zero<<<196, 256, 0, stream>>>();
  k_scatter<<<3125, 256, 0, stream>>>(src, dst);
  // weight prep
  k_wcomb<<<624, 256, 0, stream>>>(Uw, mixw);
  k_mfrag<<<96, 256, 0, stream>>>(Mw);
  k_bcomb<<<1, 192, 0, stream>>>(mixw, Ub, mixb);

  for (int L = 0; L < NL; ++L) {
    int par = L & 1;
    k_edge<<<1024, 256, 0, stream>>>(Mb, L, par);
    k_agg<<<12500, 256, 0, stream>>>(par);
    k_update<<<782, 256, 0, stream>>>(L, par, out);
  }
}

// Round 6
// 483.793 us; speedup vs baseline: 1.1451x; 1.1451x over previous
//
#include <hip/hip_runtime.h>

#define NN 50000
#define EE 800000
#define DD 64
#define NL 3
#define UIN 832
#define XW 320   // stored x row: [h | mean | mx | mn | sd]
#define DELTA_F 2.833213344056216f
#define SLOPE 0.01f
#define SCAN_BLKS 196  // 196*256 = 50176 >= NN
#define UPD_BLKS 512
#define NTILE 3125     // NN/16

typedef __attribute__((ext_vector_type(8))) short short8;
typedef __attribute__((ext_vector_type(4))) float floatx4;

// ---- static device buffers (fully rewritten every call) ----
__device__ __align__(16) float          g_hf[2][NN * DD];       // fp32 master h
__device__ __align__(16) unsigned short g_hb[2][NN * DD];       // bf16 copy for gathers
__device__ __align__(16) unsigned short g_msg[EE * DD];         // messages, CSR row order
__device__ __align__(16) unsigned short g_x2[NN * XW];          // [h | agg] bf16
__device__ __align__(16) float          g_sc[NN * 2];           // per-node (s1, s2)
__device__ __align__(16) unsigned short g_BfragU[NL * 26 * 4 * 512]; // W_comb^T fragments
__device__ __align__(16) unsigned short g_BfragM[NL * 4 * 4 * 512];  // M_w^T fragments
__device__ float g_bcomb[NL * DD];
__device__ int   g_cnt[NN];
__device__ int   g_roff[NN + 1];
__device__ __align__(16) int2 g_cedge[EE];   // (src,dst) per CSR row — one 8B record
__device__ int   g_bsum[SCAN_BLKS], g_boff[SCAN_BLKS];

__device__ __forceinline__ float bf2f(unsigned short u) {
  return __uint_as_float(((unsigned)u) << 16);
}
__device__ __forceinline__ unsigned short f2bf(float f) {
  unsigned u = __float_as_uint(f);
  return (unsigned short)((u + 0x7FFFu + ((u >> 16) & 1u)) >> 16);
}
__device__ __forceinline__ float lrelu(float x) { return x >= 0.f ? x : SLOPE * x; }

// ---- prep: h = round(h*100)/100, plus bf16 copy ----
__global__ void __launch_bounds__(256) k_prep(const float* __restrict__ h) {
  int i = blockIdx.x * 256 + threadIdx.x;
  if (i >= NN * DD) return;
  float v = rintf(h[i] * 100.f) / 100.f;
  g_hf[0][i] = v;
  g_hb[0][i] = f2bf(v);
}

__global__ void __launch_bounds__(256) k_zero() {
  int i = blockIdx.x * 256 + threadIdx.x;
  if (i < NN) g_cnt[i] = 0;
}

__global__ void __launch_bounds__(256) k_hist(const int* __restrict__ dst) {
  int i = blockIdx.x * 256 + threadIdx.x;
  if (i < EE) atomicAdd(&g_cnt[dst[i]], 1);
}

// ---- hierarchical scan: (a) per-block reduce, (b) scan partials, (c) in-block scan ----
__global__ void __launch_bounds__(256) k_scan_a() {
  __shared__ int sh[256];
  int t = threadIdx.x;
  int idx = blockIdx.x * 256 + t;
  sh[t] = (idx < NN) ? g_cnt[idx] : 0;
  __syncthreads();
  for (int off = 128; off > 0; off >>= 1) {
    if (t < off) sh[t] += sh[t + off];
    __syncthreads();
  }
  if (t == 0) g_bsum[blockIdx.x] = sh[0];
}

__global__ void __launch_bounds__(256) k_scan_b() {
  __shared__ int sh[256];
  int t = threadIdx.x;
  sh[t] = (t < SCAN_BLKS) ? g_bsum[t] : 0;
  __syncthreads();
  for (int off = 1; off < 256; off <<= 1) {
    int v = (t >= off) ? sh[t - off] : 0;
    __syncthreads();
    sh[t] += v;
    __syncthreads();
  }
  if (t < SCAN_BLKS) g_boff[t] = (t == 0) ? 0 : sh[t - 1];
}

__global__ void __launch_bounds__(256) k_scan_c() {
  __shared__ int sh[256];
  int t = threadIdx.x;
  int idx = blockIdx.x * 256 + t;
  int v = (idx < NN) ? g_cnt[idx] : 0;
  sh[t] = v;
  __syncthreads();
  for (int off = 1; off < 256; off <<= 1) {
    int x = (t >= off) ? sh[t - off] : 0;
    __syncthreads();
    sh[t] += x;
    __syncthreads();
  }
  if (idx < NN) g_roff[idx] = g_boff[blockIdx.x] + sh[t] - v;  // exclusive prefix
  if (blockIdx.x == 0 && t == 0) g_roff[NN] = EE;              // total is known
}

__global__ void __launch_bounds__(256) k_scatter(const int* __restrict__ src,
                                                 const int* __restrict__ dst) {
  int i = blockIdx.x * 256 + threadIdx.x;
  if (i < EE) {
    int d = dst[i];
    int p = atomicAdd(&g_cnt[d], 1);
    g_cedge[g_roff[d] + p] = make_int2(src[i], d);  // single 8B random write
  }
}

// ---- W_comb = mix_w @ U_w, written directly into MFMA B-fragment layout ----
__global__ void __launch_bounds__(256) k_wcomb(const float* __restrict__ Uw,
                                               const float* __restrict__ mixw) {
  int idx = blockIdx.x * 256 + threadIdx.x;  // NL*DD*UIN = 159744
  if (idx >= NL * DD * UIN) return;
  int l = idx / (DD * UIN);
  int rem = idx - l * (DD * UIN);
  int d = rem / UIN;
  int k = rem - d * UIN;
  const float* xw = mixw + (l * DD + d) * DD;
  const float* uc = Uw + (size_t)l * DD * UIN + k;
  float s = 0.f;
  for (int j = 0; j < DD; ++j) s += xw[j] * uc[(size_t)j * UIN];
  int kt = k >> 5, kr = k & 31, g = kr >> 3, j8 = kr & 7, nb = d >> 4;
  int ln = (g << 4) | (d & 15);
  g_BfragU[(((l * 26 + kt) * 4 + nb) << 9) + ln * 8 + j8] = f2bf(s);
}

__global__ void __launch_bounds__(256) k_mfrag(const float* __restrict__ Mw) {
  int idx = blockIdx.x * 256 + threadIdx.x;  // NL*DD*128 = 24576
  if (idx >= NL * DD * 128) return;
  int l = idx >> 13;
  int rem = idx & 8191;
  int d = rem >> 7;
  int k = rem & 127;
  float w = Mw[idx];
  int kt = k >> 5, kr = k & 31, g = kr >> 3, j8 = kr & 7, nb = d >> 4;
  int ln = (g << 4) | (d & 15);
  g_BfragM[(((l * 4 + kt) * 4 + nb) << 9) + ln * 8 + j8] = f2bf(w);
}

__global__ void __launch_bounds__(192) k_bcomb(const float* __restrict__ mixw,
                                               const float* __restrict__ Ub,
                                               const float* __restrict__ mixb) {
  int idx = threadIdx.x;  // 192
  int l = idx >> 6, d = idx & 63;
  const float* xw = mixw + (l * DD + d) * DD;
  const float* ub = Ub + l * DD;
  float s = 0.f;
  for (int j = 0; j < DD; ++j) s += xw[j] * ub[j];
  g_bcomb[idx] = s + mixb[idx];
}

// ---- edge GEMM: msg[row] = leaky(M @ [h_src || h_dst] + Mb), rows in CSR order ----
__global__ void __launch_bounds__(256) k_edge(const float* __restrict__ Mb,
                                              int L, int par) {
  int lane = threadIdx.x & 63;
  int wid = blockIdx.x * 4 + (threadIdx.x >> 6);
  int nw = gridDim.x * 4;
  short8 bf[16];
  const unsigned short* bp = g_BfragM + ((size_t)L * 16) * 512;
#pragma unroll
  for (int i = 0; i < 16; ++i)
    bf[i] = *(const short8*)(bp + i * 512 + lane * 8);
  float mb[4];
#pragma unroll
  for (int nb = 0; nb < 4; ++nb) mb[nb] = Mb[L * DD + nb * 16 + (lane & 15)];
  const unsigned short* hb = g_hb[par];
  int chunk = (lane >> 4) << 3;

  for (int wt = wid; wt < EE / 16; wt += nw) {
    int2 e = g_cedge[wt * 16 + (lane & 15)];   // coalesced 8B CSR edge record
    int sn = e.x, dn = e.y;
    floatx4 acc[4];
#pragma unroll
    for (int nb = 0; nb < 4; ++nb)
#pragma unroll
      for (int r = 0; r < 4; ++r) acc[nb][r] = 0.f;
#pragma unroll
    for (int kk = 0; kk < 4; ++kk) {
      int node = (kk < 2) ? sn : dn;
      short8 a = *(const short8*)(hb + node * DD + (kk & 1) * 32 + chunk);
#pragma unroll
      for (int nb = 0; nb < 4; ++nb)
        acc[nb] = __builtin_amdgcn_mfma_f32_16x16x32_bf16(a, bf[kk * 4 + nb], acc[nb], 0, 0, 0);
    }
#pragma unroll
    for (int nb = 0; nb < 4; ++nb) {
#pragma unroll
      for (int r = 0; r < 4; ++r) {
        float v = lrelu(acc[nb][r] + mb[nb]);
        int row = wt * 16 + 4 * (lane >> 4) + r;
        g_msg[row * DD + nb * 16 + (lane & 15)] = f2bf(v);
      }
    }
  }
}

// ---- per-node aggregation -> x2 row [h | mean | mx | mn | sd] + (s1,s2) ----
__global__ void __launch_bounds__(256) k_agg(int par) {
  int lane = threadIdx.x & 63;
  int n = blockIdx.x * 4 + (threadIdx.x >> 6);
  int r0 = g_roff[n], r1 = g_roff[n + 1];
  float s = 0.f, q = 0.f, mx = -3.4e38f, mn = 3.4e38f;
  for (int r = r0; r < r1; ++r) {
    float v = bf2f(g_msg[r * DD + lane]);
    s += v;
    q += v * v;
    mx = fmaxf(mx, v);
    mn = fminf(mn, v);
  }
  float deg = (float)(r1 - r0);
  float degc = fmaxf(deg, 1.f);
  float mean = s / degc;
  float var = fmaxf(q / degc - mean * mean, 0.f);
  float sd = sqrtf(var + 1e-30f);
  if (r1 == r0) { mx = 0.f; mn = 0.f; sd = 0.f; }
  float logd = logf(fmaxf(deg, 1.f) + 1.f);
  unsigned short* xp = g_x2 + (size_t)n * XW;
  xp[lane] = g_hb[par][n * DD + lane];
  xp[64 + lane] = f2bf(mean);
  xp[128 + lane] = f2bf(mx);
  xp[192 + lane] = f2bf(mn);
  xp[256 + lane] = f2bf(sd);
  if (lane == 0) {
    g_sc[n * 2]     = logd / DELTA_F;
    g_sc[n * 2 + 1] = DELTA_F / logd;
  }
}

// ---- fused U+mix GEMM, N-split across waves: wave w owns cols [w*16, w*16+16) ----
// B fragments (26 short8) live in registers for the whole kernel; grid-stride tiles.
__global__ void __launch_bounds__(256, 2) k_update(int L, int par, float* __restrict__ out) {
  int lane = threadIdx.x & 63;
  int nb = threadIdx.x >> 6;         // wave id == output col block
  int chunk = (lane >> 4) << 3;
  const unsigned short* bp = g_BfragU + (size_t)L * 26 * 4 * 512;

  // load this wave's B fragments once
  short8 Bf[26];
#pragma unroll
  for (int i = 0; i < 26; ++i)
    Bf[i] = *(const short8*)(bp + ((i * 4 + nb) << 9) + lane * 8);
  float bc = g_bcomb[L * DD + nb * 16 + (lane & 15)];

  float csum = 0.f;
  for (int wt = blockIdx.x; wt < NTILE; wt += gridDim.x) {
    int rbase = wt * 16;
    const unsigned short* ap = g_x2 + (size_t)(rbase + (lane & 15)) * XW;
    floatx4 acc0, acc2, acc3;
#pragma unroll
    for (int r = 0; r < 4; ++r) { acc0[r] = 0.f; acc2[r] = 0.f; acc3[r] = 0.f; }
    // group 0: kt 0..9 over x2 cols [0,320)
#pragma unroll
    for (int kk = 0; kk < 10; ++kk) {
      short8 a = *(const short8*)(ap + kk * 32 + chunk);
      acc0 = __builtin_amdgcn_mfma_f32_16x16x32_bf16(a, Bf[kk], acc0, 0, 0, 0);
    }
    // groups 2,3: kt 10..17 and 18..25 over the SAME agg cols [64,320)
#pragma unroll
    for (int kk = 0; kk < 8; ++kk) {
      short8 a = *(const short8*)(ap + 64 + kk * 32 + chunk);
      acc2 = __builtin_amdgcn_mfma_f32_16x16x32_bf16(a, Bf[10 + kk], acc2, 0, 0, 0);
      acc3 = __builtin_amdgcn_mfma_f32_16x16x32_bf16(a, Bf[18 + kk], acc3, 0, 0, 0);
    }
    // epilogue: scalers, leaky, residual, relu, store
#pragma unroll
    for (int r = 0; r < 4; ++r) {
      int row = rbase + 4 * (lane >> 4) + r;
      float s1 = g_sc[row * 2], s2 = g_sc[row * 2 + 1];
      int col = nb * 16 + (lane & 15);
      float y = lrelu(acc0[r] + s1 * acc2[r] + s2 * acc3[r] + bc);
      float hn = fmaxf(y + g_hf[par][row * DD + col], 0.f);
      g_hf[par ^ 1][row * DD + col] = hn;
      g_hb[par ^ 1][row * DD + col] = f2bf(hn);
      csum += hn;
    }
  }
  if (L == 2) {
    csum += __shfl_xor(csum, 16);
    csum += __shfl_xor(csum, 32);
    if ((lane >> 4) == 0) atomicAdd(out + nb * 16 + lane, csum);
  }
}

extern "C" void kernel_launch(void* const* d_in, const int* in_sizes, int n_in,
                              void* d_out, int out_size, void* d_ws, size_t ws_size,
                              hipStream_t stream) {
  const float* h    = (const float*)d_in[0];
  const int*   src  = (const int*)d_in[1];
  const int*   dst  = (const int*)d_in[2];
  const float* Mw   = (const float*)d_in[3];
  const float* Mb   = (const float*)d_in[4];
  const float* Uw   = (const float*)d_in[5];
  const float* Ub   = (const float*)d_in[6];
  const float* mixw = (const float*)d_in[7];
  const float* mixb = (const float*)d_in[8];
  float* out = (float*)d_out;

  hipMemsetAsync(out, 0, (size_t)out_size * sizeof(float), stream);

  k_prep<<<12500, 256, 0, stream>>>(h);
  // CSR build (dst constant across layers -> once per call)
  k_zero<<<196, 256, 0, stream>>>();
  k_hist<<<3125, 256, 0, stream>>>(dst);
  k_scan_a<<<SCAN_BLKS, 256, 0, stream>>>();
  k_scan_b<<<1, 256, 0, stream>>>();
  k_scan_c<<<SCAN_BLKS, 256, 0, stream>>>();
  k_zero<<<196, 256, 0, stream>>>();
  k_scatter<<<3125, 256, 0, stream>>>(src, dst);
  // weight prep
  k_wcomb<<<624, 256, 0, stream>>>(Uw, mixw);
  k_mfrag<<<96, 256, 0, stream>>>(Mw);
  k_bcomb<<<1, 192, 0, stream>>>(mixw, Ub, mixb);

  for (int L = 0; L < NL; ++L) {
    int par = L & 1;
    k_edge<<<1024, 256, 0, stream>>>(Mb, L, par);
    k_agg<<<12500, 256, 0, stream>>>(par);
    k_update<<<UPD_BLKS, 256, 0, stream>>>(L, par, out);
  }
}